// Round 5
// baseline (125.339 us; speedup 1.0000x reference)
//
#include <hip/hip_runtime.h>
#include <math.h>

// Problem constants (fixed by setup_inputs)
#define BATCH 8
#define HI 512
#define WI 512
#define HO 256
#define WO 256
#define PLANE (HI*WI)          // 262144 per channel
#define OPIX (HO*WO)           // 65536 output pixels per batch
// Block tile: 64 iw-cols x 4 ih-rows, 1 pixel per thread.
// Gather footprint for iw in [w0,w0+64): image rows/cols in [w0+2, w0+70).
#define LROWS 68
#define LCOLS 10
#define LQ 11                  // float4 per row: 10 data + 1 pad (176 B, 16B-aligned)

// Max-occupancy experiment: cap at 64 VGPR (8 waves/EU) — the m69 cliff.
__global__ __launch_bounds__(256, 8) void downsampler_kernel(
    const float* __restrict__ images,
    const float* __restrict__ kernels,
    const float* __restrict__ offx,
    const float* __restrict__ offy,
    float* __restrict__ out)
{
    __shared__ float4 simg[LROWS * LQ];   // 11968 B

    const int blk  = blockIdx.x;          // 2048 blocks
    const int b    = blk >> 8;            // batch
    const int ihx  = (blk >> 2) & 63;     // ih-tile (4 rows)
    const int w0   = (blk & 3) << 6;      // iw-tile base (64 cols)
    const int tid  = threadIdx.x;
    const int lane = tid & 63;
    const int iw   = w0 + lane;
    const int ih   = (ihx << 2) + (tid >> 6);   // wave-uniform

    // ---- Stage the 68x10 band as RGBX float4 into LDS ----
    // I(r, c, .) = simg[(r-(w0+2))*11 + (c-(r-4))], r in [w0+2, w0+70)
    {
        const float* imb = images + (size_t)b * 3 * PLANE;
        for (int i = tid; i < LROWS * LCOLS; i += 256) {
            const int row = i / LCOLS;
            const int col = i - row * LCOLS;
            const int r = w0 + 2 + row;
            int c = r - 4 + col;
            c = c < 0 ? 0 : c;   // upper clamp provably inactive (c <= 267)
            const float* src = imb + r * WI + c;
            simg[row * LQ + col] =
                make_float4(src[0], src[PLANE], src[2 * PLANE], 0.0f);
        }
    }
    __syncthreads();

    const bool flip = (ih < 128);          // wave-uniform
    const float* offxb = offx    + (size_t)b * 9 * OPIX;
    const float* offyb = offy    + (size_t)b * 9 * OPIX;
    const float* kernb = kernels + (size_t)b * 9 * OPIX;

    const int pl   = ih * WO + iw;
    const int pix2 = pl & (OPIX / 2 - 1);  // float2 index of scrambled pair (2pl, 2pl+1)

    const float uu_own = (float)iw + 0.5f;
    const float uu_s0  = (float)((2 * iw) & 255) + 0.5f;
    const float uu_s1  = uu_s0 + 1.0f;     // no wrap: (2iw)&255 is even <= 254

    float acc0 = 0.f, acc1 = 0.f, acc2 = 0.f;

    #pragma unroll
    for (int k = 0; k < 9; ++k) {
        // ---- per-tap global loads (compiler pipelines across unrolled taps) ----
        const float oxv = offxb[k * OPIX + pl];
        const float oyv = offyb[k * OPIX + pl];
        const float kvv = kernb[k * OPIX + pl];
        // scrambled weight sources for taps t=2k (ks_a@pixel 2pl or 2pl+1) and t=2k+1
        const int ta = 2 * k, tb = 2 * k + 1;
        const int sel_a = (ta >= 9) ? 1 : 0;
        const int sel_b = (tb >= 9) ? 1 : 0;
        const int ks_a = ta - 9 * sel_a;
        const int ks_b = tb - 9 * sel_b;
        const float2 sxa = ((const float2*)(offxb + ks_a * OPIX))[pix2];
        const float2 sya = ((const float2*)(offyb + ks_a * OPIX))[pix2];
        const float2 sxb = ((const float2*)(offxb + ks_b * OPIX))[pix2];
        const float2 syb = ((const float2*)(offyb + ks_b * OPIX))[pix2];

        // ---- own coords -> gather corners from LDS ----
        const float kxf = (float)(k / 3);
        const float kyf = (float)(k - 3 * (k / 3));
        const float cx = ((oxv + 1.5f) + kxf) + uu_own;
        const float cy = ((oyv + 1.5f) + kyf) + uu_own;
        const int x0 = (int)floorf(cx);        // row in [iw+2, iw+4]
        const int y0 = (int)floorf(cy);        // col in [iw+2, iw+4]
        const int rowrel = x0 - 2 - w0;        // [lane, lane+2]
        const int colq   = y0 - x0 + 4;        // [2, 6]
        // single LDS address; corners via immediate offsets
        const float4* qa = &simg[rowrel * LQ + (colq - 1)];
        const float4 Ia = qa[1];               // (x0,y0)
        const float4 Ib = qa[2];               // (x0,y1)
        const float4 Ic = qa[LQ];              // (x1,y0)
        const float4 Id = qa[LQ + 1];          // (x1,y1)

        // ---- scrambled weights ----
        const float uu_a = sel_a ? uu_s1 : uu_s0;
        const float uu_b = sel_b ? uu_s1 : uu_s0;
        const float oxa  = sel_a ? sxa.y : sxa.x;
        const float oya  = sel_a ? sya.y : sya.x;
        const float oxb2 = sel_b ? sxb.y : sxb.x;
        const float oyb2 = sel_b ? syb.y : syb.x;
        const float kxa = (float)(ks_a / 3), kya = (float)(ks_a - 3 * (ks_a / 3));
        const float kxb = (float)(ks_b / 3), kyb = (float)(ks_b - 3 * (ks_b / 3));

        // reference fp32 op order: ((off + 1.5) + k?) + u
        const float cxa = ((oxa + 1.5f) + kxa) + uu_a;
        const float cya = ((oya + 1.5f) + kya) + uu_a;
        const float cxb = ((oxb2 + 1.5f) + kxb) + uu_b;
        const float cyb = ((oyb2 + 1.5f) + kyb) + uu_b;
        const float fxa = cxa - floorf(cxa);   // exact (Sterbenz)
        const float fya = cya - floorf(cya);
        const float fxb = cxb - floorf(cxb);
        const float fyb = cyb - floorf(cyb);
        const float w0w = flip ? (1.0f - fxa) : fxa;   // wx[2k]
        const float w1w = flip ? (1.0f - fxb) : fxb;   // wx[2k+1]
        const float v0w = flip ? (1.0f - fya) : fya;   // wy[2k]
        const float v1w = flip ? (1.0f - fyb) : fyb;   // wy[2k+1]

        const float w0v0 = w0w * v0w, w1v0 = w1w * v0w;
        const float w0v1 = w0w * v1w, w1v1 = w1w * v1w;

        // scrambled channel/corner table
        const float p0 = w0v0 * Ib.x + w1v0 * Ic.x + w0v1 * Id.y + w1v1 * Ia.z;
        const float p1 = w0v0 * Ia.x + w1v0 * Ib.y + w0v1 * Ic.y + w1v1 * Id.z;
        const float p2 = w0v0 * Id.x + w1v0 * Ia.y + w0v1 * Ib.z + w1v1 * Ic.z;

        acc0 += kvv * p0;
        acc1 += kvv * p1;
        acc2 += kvv * p2;
    }

    // ---- softround(out * 255) via HW sin (input in revolutions) ----
    const float TWO_PI_INV = 0.15915494309189533577f;
    const size_t obase = ((size_t)b * OPIX + (size_t)pl) * 3;
    const float z0 = acc0 * 255.0f;
    const float z1 = acc1 * 255.0f;
    const float z2 = acc2 * 255.0f;
    const float r0s = z0 - rintf(z0);   // exact; sin(2*pi*z) = sin(2*pi*r)
    const float r1s = z1 - rintf(z1);
    const float r2s = z2 - rintf(z2);
    out[obase + 0] = z0 - __builtin_amdgcn_sinf(r0s) * TWO_PI_INV;
    out[obase + 1] = z1 - __builtin_amdgcn_sinf(r1s) * TWO_PI_INV;
    out[obase + 2] = z2 - __builtin_amdgcn_sinf(r2s) * TWO_PI_INV;
}

extern "C" void kernel_launch(void* const* d_in, const int* in_sizes, int n_in,
                              void* d_out, int out_size, void* d_ws, size_t ws_size,
                              hipStream_t stream) {
    const float* images  = (const float*)d_in[0];
    const float* kernels = (const float*)d_in[1];
    const float* offx    = (const float*)d_in[2];
    const float* offy    = (const float*)d_in[3];
    float* out = (float*)d_out;

    dim3 grid(BATCH * 64 * 4);   // 2048 blocks: (b, ih-tile of 4, iw-tile of 64)
    dim3 block(256);             // 64 iw-lanes x 4 waves, 1 pixel per thread
    hipLaunchKernelGGL(downsampler_kernel, grid, block, 0, stream,
                       images, kernels, offx, offy, out);
}

// Round 6
// 118.310 us; speedup vs baseline: 1.0594x; 1.0594x over previous
//
#include <hip/hip_runtime.h>
#include <math.h>

// Problem constants (fixed by setup_inputs)
#define BATCH 8
#define HI 512
#define WI 512
#define HO 256
#define WO 256
#define PLANE (HI*WI)          // 262144 per channel
#define OPIX (HO*WO)           // 65536 output pixels per batch
// Block: 2 ih-rows x 64 iw-cols, 3 tap-groups (3 taps/thread) = 384 threads.
// Gather footprint for iw in [w0,w0+64): image rows/cols in [w0+2, w0+70).
#define LROWS 68
#define LCOLS 10
#define LQ 11                  // float4 per row: 10 data + 1 pad (176 B, 16B-aligned)

__global__ __launch_bounds__(384) void downsampler_kernel(
    const float* __restrict__ images,
    const float* __restrict__ kernels,
    const float* __restrict__ offx,
    const float* __restrict__ offy,
    float* __restrict__ out)
{
    __shared__ float4 simg[LROWS * LQ];       // 11968 B image band
    __shared__ float  pbuf[2 * 3 * 64 * 3];   // 4608 B tap partials [row][grp][px][ch]

    const int blk  = blockIdx.x;              // 4096 blocks
    const int b    = blk >> 9;                // batch
    const int ihx  = (blk >> 2) & 127;        // 2-row tile index
    const int w0   = (blk & 3) << 6;          // iw-tile base
    const int tid  = threadIdx.x;
    const int lane = tid & 63;
    const int grp  = __builtin_amdgcn_readfirstlane(tid >> 6);  // 0..5, wave-uniform
    const int g    = grp % 3;                 // tap group: taps 3g..3g+2
    const int rsel = grp / 3;                 // which of the 2 rows
    const int ih0  = ihx << 1;
    const int ih   = ih0 + rsel;
    const int iw   = w0 + lane;

    // ---- Stage the 68x10 band as RGBX float4 into LDS ----
    // I(r, c, .) = simg[(r-(w0+2))*11 + (c-(r-4))], r in [w0+2, w0+70)
    {
        const float* imb = images + (size_t)b * 3 * PLANE;
        for (int i = tid; i < LROWS * LCOLS; i += 384) {
            const int row = i / LCOLS;
            const int col = i - row * LCOLS;
            const int r = w0 + 2 + row;
            int c = r - 4 + col;
            c = c < 0 ? 0 : c;   // upper clamp provably inactive (c <= 266)
            const float* src = imb + r * WI + c;
            simg[row * LQ + col] =
                make_float4(src[0], src[PLANE], src[2 * PLANE], 0.0f);
        }
    }
    __syncthreads();

    const bool flip = (ih0 < 128);            // uniform per block (ih0 even)
    const float* offxb = offx    + (size_t)b * 9 * OPIX;
    const float* offyb = offy    + (size_t)b * 9 * OPIX;
    const float* kernb = kernels + (size_t)b * 9 * OPIX;

    const int pl   = ih * WO + iw;
    const int pix2 = pl & (OPIX / 2 - 1);     // float2 index of scrambled pair (2pl, 2pl+1)
    const float uu_own = (float)iw + 0.5f;
    const float uu_s0  = (float)((2 * iw) & 255) + 0.5f;  // col of source pixel 2pl
    const float uu_s1  = uu_s0 + 1.0f;                     // col of 2pl+1 (no wrap: even<=254)

    float a0 = 0.f, a1 = 0.f, a2 = 0.f;

    #pragma unroll
    for (int j = 0; j < 3; ++j) {
        const int k = 3 * g + j;              // tap (wave-uniform scalar)
        // ---- global loads for this tap ----
        const float oxv = offxb[k * OPIX + pl];
        const float oyv = offyb[k * OPIX + pl];
        const float kvv = kernb[k * OPIX + pl];
        const int ta = 2 * k, tb = 2 * k + 1;
        const int sel_a = (ta >= 9) ? 1 : 0;
        const int sel_b = (tb >= 9) ? 1 : 0;
        const int ks_a = ta - 9 * sel_a;
        const int ks_b = tb - 9 * sel_b;
        const float2 sxa = ((const float2*)(offxb + ks_a * OPIX))[pix2];
        const float2 sya = ((const float2*)(offyb + ks_a * OPIX))[pix2];
        const float2 sxb = ((const float2*)(offxb + ks_b * OPIX))[pix2];
        const float2 syb = ((const float2*)(offyb + ks_b * OPIX))[pix2];

        // ---- own coords -> gather corners from LDS ----
        // k = 3g+j  =>  kx = k/3 = g, ky = k%3 = j
        const float kxf = (float)g;
        const float kyf = (float)j;
        const float cx = ((oxv + 1.5f) + kxf) + uu_own;   // reference fp32 op order
        const float cy = ((oyv + 1.5f) + kyf) + uu_own;
        const int x0 = (int)floorf(cx);        // row in [iw+2, iw+5]
        const int y0 = (int)floorf(cy);        // col in [iw+2, iw+5]
        const int rowrel = x0 - 2 - w0;        // [lane, lane+3]
        const int colq   = y0 - x0 + 4;        // [1, 7]
        const float4* qa = &simg[rowrel * LQ + (colq - 1)];
        const float4 Ia = qa[1];               // (x0,y0)
        const float4 Ib = qa[2];               // (x0,y1)
        const float4 Ic = qa[LQ];              // (x1,y0)
        const float4 Id = qa[LQ + 1];          // (x1,y1)

        // ---- scrambled weights for taps t=2k, 2k+1 ----
        const float uu_a = sel_a ? uu_s1 : uu_s0;
        const float uu_b = sel_b ? uu_s1 : uu_s0;
        const float oxa  = sel_a ? sxa.y : sxa.x;
        const float oya  = sel_a ? sya.y : sya.x;
        const float oxb2 = sel_b ? sxb.y : sxb.x;
        const float oyb2 = sel_b ? syb.y : syb.x;
        const float kxa = (float)(ks_a / 3), kya = (float)(ks_a - 3 * (ks_a / 3));
        const float kxb = (float)(ks_b / 3), kyb = (float)(ks_b - 3 * (ks_b / 3));

        const float cxa = ((oxa + 1.5f) + kxa) + uu_a;    // reference fp32 op order
        const float cya = ((oya + 1.5f) + kya) + uu_a;
        const float cxb = ((oxb2 + 1.5f) + kxb) + uu_b;
        const float cyb = ((oyb2 + 1.5f) + kyb) + uu_b;
        const float fxa = cxa - floorf(cxa);   // exact (Sterbenz)
        const float fya = cya - floorf(cya);
        const float fxb = cxb - floorf(cxb);
        const float fyb = cyb - floorf(cyb);
        const float w0w = flip ? (1.0f - fxa) : fxa;   // wx[2k]
        const float w1w = flip ? (1.0f - fxb) : fxb;   // wx[2k+1]
        const float v0w = flip ? (1.0f - fya) : fya;   // wy[2k]
        const float v1w = flip ? (1.0f - fyb) : fyb;   // wy[2k+1]

        const float w0v0 = w0w * v0w, w1v0 = w1w * v0w;
        const float w0v1 = w0w * v1w, w1v1 = w1w * v1w;

        // scrambled channel/corner table
        const float p0 = w0v0 * Ib.x + w1v0 * Ic.x + w0v1 * Id.y + w1v1 * Ia.z;
        const float p1 = w0v0 * Ia.x + w1v0 * Ib.y + w0v1 * Ic.y + w1v1 * Id.z;
        const float p2 = w0v0 * Id.x + w1v0 * Ia.y + w0v1 * Ib.z + w1v1 * Ic.z;

        a0 += kvv * p0;
        a1 += kvv * p1;
        a2 += kvv * p2;
    }

    // ---- write tap-group partials ----
    // pbuf layout: [(grp)*64 + px]*3 + ch, grp = rsel*3+g (== tid>>6)
    {
        const int pb = (grp * 64 + lane) * 3;   // lanes stride 3: gcd(3,32)=1, conflict-free
        pbuf[pb + 0] = a0;
        pbuf[pb + 1] = a1;
        pbuf[pb + 2] = a2;
    }
    __syncthreads();

    // ---- reduce 3 tap-groups + softround + coalesced store ----
    {
        const int r   = tid / 192;              // 0,1 : which ih-row
        const int idx = tid - r * 192;          // px*3+ch within the row
        const float s = pbuf[r * 576 + idx]
                      + pbuf[r * 576 + 192 + idx]
                      + pbuf[r * 576 + 384 + idx];
        const float z  = s * 255.0f;
        const float rs = z - rintf(z);          // exact; sin(2*pi*z) = sin(2*pi*rs)
        const float TWO_PI_INV = 0.15915494309189533577f;
        out[((size_t)b * OPIX + (size_t)(ih0 + r) * WO + w0) * 3 + idx] =
            z - __builtin_amdgcn_sinf(rs) * TWO_PI_INV;
    }
}

extern "C" void kernel_launch(void* const* d_in, const int* in_sizes, int n_in,
                              void* d_out, int out_size, void* d_ws, size_t ws_size,
                              hipStream_t stream) {
    const float* images  = (const float*)d_in[0];
    const float* kernels = (const float*)d_in[1];
    const float* offx    = (const float*)d_in[2];
    const float* offy    = (const float*)d_in[3];
    float* out = (float*)d_out;

    dim3 grid(BATCH * 128 * 4);  // 4096 blocks: (b, 2-row tile, 64-col tile)
    dim3 block(384);             // 64 lanes x 6 waves (2 rows x 3 tap-groups)
    hipLaunchKernelGGL(downsampler_kernel, grid, block, 0, stream,
                       images, kernels, offx, offy, out);
}

// Round 7
// 113.861 us; speedup vs baseline: 1.1008x; 1.0391x over previous
//
#include <hip/hip_runtime.h>
#include <math.h>

// Problem constants (fixed by setup_inputs)
#define BATCH 8
#define HI 512
#define WI 512
#define HO 256
#define WO 256
#define PLANE (HI*WI)          // 262144 per channel
#define OPIX (HO*WO)           // 65536 output pixels per batch
// Block tile: 64 iw-cols x 4 ih-rows, 1 pixel per thread.
// Gather footprint for iw in [w0,w0+64): image rows/cols in [w0+2, w0+70).
#define LROWS 68
#define LCOLS 10
#define LQ 11                  // float4 per row: 10 data + 1 pad (176 B, 16B-aligned)

__global__ __launch_bounds__(256) void downsampler_kernel(
    const float* __restrict__ images,
    const float* __restrict__ kernels,
    const float* __restrict__ offx,
    const float* __restrict__ offy,
    float* __restrict__ out)
{
    __shared__ float4 simg[LROWS * LQ];   // 11968 B

    const int blk  = blockIdx.x;          // 2048 blocks
    const int b    = blk >> 8;            // batch
    const int ihx  = (blk >> 2) & 63;     // ih-tile (4 rows)
    const int w0   = (blk & 3) << 6;      // iw-tile base (64 cols)
    const int tid  = threadIdx.x;
    const int lane = tid & 63;
    const int iw   = w0 + lane;
    const int ih   = (ihx << 2) + (tid >> 6);   // wave-uniform

    const float* offxb = offx    + (size_t)b * 9 * OPIX;
    const float* offyb = offy    + (size_t)b * 9 * OPIX;
    const float* kernb = kernels + (size_t)b * 9 * OPIX;

    const int pl   = ih * WO + iw;
    const int pix2 = pl & (OPIX / 2 - 1);  // float2 index of scrambled pair (2pl, 2pl+1)

    // ==== PHASE 1: issue ALL compulsory global loads back-to-back (max MLP) ====
    // 27 dword + 18 dwordx2 = 45 loads, ~16 KB per wave in flight.
    float  ox_[9], oy_[9], kv_[9];
    float2 sx_[9], sy_[9];
    #pragma unroll
    for (int k = 0; k < 9; ++k) {
        ox_[k] = offxb[k * OPIX + pl];
        oy_[k] = offyb[k * OPIX + pl];
        kv_[k] = kernb[k * OPIX + pl];
        sx_[k] = ((const float2*)(offxb + k * OPIX))[pix2];
        sy_[k] = ((const float2*)(offyb + k * OPIX))[pix2];
    }

    // ---- image band staging (issued after the batch; single FIFO drain) ----
    // I(r, c, .) = simg[(r-(w0+2))*11 + (c-(r-4))], r in [w0+2, w0+70)
    {
        const float* imb = images + (size_t)b * 3 * PLANE;
        #pragma unroll
        for (int ii = 0; ii < 3; ++ii) {
            const int i = tid + ii * 256;
            if (i < LROWS * LCOLS) {
                const int row = i / LCOLS;
                const int col = i - row * LCOLS;
                const int r = w0 + 2 + row;
                int c = r - 4 + col;
                c = c < 0 ? 0 : c;   // upper clamp provably inactive (c <= 266)
                const float* src = imb + r * WI + c;
                simg[row * LQ + col] =
                    make_float4(src[0], src[PLANE], src[2 * PLANE], 0.0f);
            }
        }
    }
    __builtin_amdgcn_sched_barrier(0);   // pin the load batch above all uses
    __syncthreads();

    // ==== PHASE 2: pure compute from registers + LDS ====
    const bool flip = (ih < 128);          // wave-uniform
    const float uu_own = (float)iw + 0.5f;
    const float uu_s0  = (float)((2 * iw) & 255) + 0.5f;
    const float uu_s1  = uu_s0 + 1.0f;     // no wrap: (2iw)&255 is even <= 254

    float acc0 = 0.f, acc1 = 0.f, acc2 = 0.f;

    #pragma unroll
    for (int k = 0; k < 9; ++k) {
        // ---- own coords -> gather corners from LDS ----
        const float kxf = (float)(k / 3);
        const float kyf = (float)(k - 3 * (k / 3));
        const float cx = ((ox_[k] + 1.5f) + kxf) + uu_own;   // reference fp32 op order
        const float cy = ((oy_[k] + 1.5f) + kyf) + uu_own;
        const int x0 = (int)floorf(cx);        // row in [iw+2, iw+5]
        const int y0 = (int)floorf(cy);        // col in [iw+2, iw+5]
        const int rowrel = x0 - 2 - w0;        // [lane, lane+3]
        const int colq   = y0 - x0 + 4;        // [1, 7]
        const float4* qa = &simg[rowrel * LQ + (colq - 1)];
        const float4 Ia = qa[1];               // (x0,y0)
        const float4 Ib = qa[2];               // (x0,y1)
        const float4 Ic = qa[LQ];              // (x1,y0)
        const float4 Id = qa[LQ + 1];          // (x1,y1)

        // ---- scrambled weights for taps t=2k, 2k+1 ----
        const int ta = 2 * k, tb = 2 * k + 1;
        const int sel_a = (ta >= 9) ? 1 : 0;
        const int sel_b = (tb >= 9) ? 1 : 0;
        const int ks_a = ta - 9 * sel_a;
        const int ks_b = tb - 9 * sel_b;
        const float uu_a = sel_a ? uu_s1 : uu_s0;
        const float uu_b = sel_b ? uu_s1 : uu_s0;
        const float oxa  = sel_a ? sx_[ks_a].y : sx_[ks_a].x;
        const float oya  = sel_a ? sy_[ks_a].y : sy_[ks_a].x;
        const float oxb2 = sel_b ? sx_[ks_b].y : sx_[ks_b].x;
        const float oyb2 = sel_b ? sy_[ks_b].y : sy_[ks_b].x;
        const float kxa = (float)(ks_a / 3), kya = (float)(ks_a - 3 * (ks_a / 3));
        const float kxb = (float)(ks_b / 3), kyb = (float)(ks_b - 3 * (ks_b / 3));

        const float cxa = ((oxa + 1.5f) + kxa) + uu_a;    // reference fp32 op order
        const float cya = ((oya + 1.5f) + kya) + uu_a;
        const float cxb = ((oxb2 + 1.5f) + kxb) + uu_b;
        const float cyb = ((oyb2 + 1.5f) + kyb) + uu_b;
        const float fxa = cxa - floorf(cxa);   // exact (Sterbenz)
        const float fya = cya - floorf(cya);
        const float fxb = cxb - floorf(cxb);
        const float fyb = cyb - floorf(cyb);
        const float w0w = flip ? (1.0f - fxa) : fxa;   // wx[2k]
        const float w1w = flip ? (1.0f - fxb) : fxb;   // wx[2k+1]
        const float v0w = flip ? (1.0f - fya) : fya;   // wy[2k]
        const float v1w = flip ? (1.0f - fyb) : fyb;   // wy[2k+1]

        const float w0v0 = w0w * v0w, w1v0 = w1w * v0w;
        const float w0v1 = w0w * v1w, w1v1 = w1w * v1w;

        // scrambled channel/corner table
        const float p0 = w0v0 * Ib.x + w1v0 * Ic.x + w0v1 * Id.y + w1v1 * Ia.z;
        const float p1 = w0v0 * Ia.x + w1v0 * Ib.y + w0v1 * Ic.y + w1v1 * Id.z;
        const float p2 = w0v0 * Id.x + w1v0 * Ia.y + w0v1 * Ib.z + w1v1 * Ic.z;

        acc0 += kv_[k] * p0;
        acc1 += kv_[k] * p1;
        acc2 += kv_[k] * p2;
    }

    // ---- softround(out * 255) via HW sin (input in revolutions) ----
    const float TWO_PI_INV = 0.15915494309189533577f;
    const size_t obase = ((size_t)b * OPIX + (size_t)pl) * 3;
    const float z0 = acc0 * 255.0f;
    const float z1 = acc1 * 255.0f;
    const float z2 = acc2 * 255.0f;
    const float r0s = z0 - rintf(z0);   // exact; sin(2*pi*z) = sin(2*pi*r)
    const float r1s = z1 - rintf(z1);
    const float r2s = z2 - rintf(z2);
    out[obase + 0] = z0 - __builtin_amdgcn_sinf(r0s) * TWO_PI_INV;
    out[obase + 1] = z1 - __builtin_amdgcn_sinf(r1s) * TWO_PI_INV;
    out[obase + 2] = z2 - __builtin_amdgcn_sinf(r2s) * TWO_PI_INV;
}

extern "C" void kernel_launch(void* const* d_in, const int* in_sizes, int n_in,
                              void* d_out, int out_size, void* d_ws, size_t ws_size,
                              hipStream_t stream) {
    const float* images  = (const float*)d_in[0];
    const float* kernels = (const float*)d_in[1];
    const float* offx    = (const float*)d_in[2];
    const float* offy    = (const float*)d_in[3];
    float* out = (float*)d_out;

    dim3 grid(BATCH * 64 * 4);   // 2048 blocks: (b, ih-tile of 4, iw-tile of 64)
    dim3 block(256);             // 64 iw-lanes x 4 waves, 1 pixel per thread
    hipLaunchKernelGGL(downsampler_kernel, grid, block, 0, stream,
                       images, kernels, offx, offy, out);
}